// Round 4
// baseline (1423.837 us; speedup 1.0000x reference)
//
#include <hip/hip_runtime.h>
#include <hip/hip_bf16.h>

#define B_ 8
#define T_ 2048
#define D_ 1024
#define W_ 64
#define LN_EPS 1e-5f
#define LOG2E 1.4426950408889634f

typedef __attribute__((ext_vector_type(8))) short bf16x8;
typedef __attribute__((ext_vector_type(4))) float f32x4;
typedef __attribute__((ext_vector_type(2))) float f32x2;
typedef unsigned short ushort_t;

__device__ __forceinline__ ushort_t f32_to_bf16(float f) {
    union { float ff; unsigned u; } c; c.ff = f;
    unsigned r = (c.u + 0x7fffu + ((c.u >> 16) & 1u)) >> 16;
    return (ushort_t)r;
}
__device__ __forceinline__ float bf16_to_f32(ushort_t h) {
    union { unsigned u; float f; } c; c.u = ((unsigned)h) << 16; return c.f;
}
__device__ __forceinline__ float tanh_fast(float x) {
    float xx = fminf(fmaxf(x, -20.f), 20.f);
    float e = __expf(2.f * xx);
    return 1.f - 2.f / (e + 1.f);
}
__device__ __forceinline__ float readlane_f(float v, int l) {
    return __int_as_float(__builtin_amdgcn_readlane(__float_as_int(v), l));
}
// DPP-based add with immediate control (template => constant integer)
template <int CTRL>
__device__ __forceinline__ float dpp_add(float x) {
    int y = __builtin_amdgcn_update_dpp(0, __float_as_int(x), CTRL, 0xf, 0xf, true);
    return x + __int_as_float(y);
}
// Packed pair reduction: one DPP chain reduces both components.
template <int CTRL>
__device__ __forceinline__ f32x2 pk_dpp_add(f32x2 v) {
    f32x2 t;
    t.x = __int_as_float(__builtin_amdgcn_update_dpp(0, __float_as_int(v.x), CTRL, 0xf, 0xf, true));
    t.y = __int_as_float(__builtin_amdgcn_update_dpp(0, __float_as_int(v.y), CTRL, 0xf, 0xf, true));
    return v + t;
}
__device__ __forceinline__ f32x2 sum64_pair(f32x2 v) {
    v = pk_dpp_add<0x111>(v);  // row_shr:1
    v = pk_dpp_add<0x112>(v);  // row_shr:2
    v = pk_dpp_add<0x114>(v);  // row_shr:4
    v = pk_dpp_add<0x118>(v);  // row_shr:8
    v = pk_dpp_add<0x142>(v);  // row_bcast:15
    v = pk_dpp_add<0x143>(v);  // row_bcast:31 -> lane63 = totals
    return v;
}
// Scalar 64-lane sum; total lands in lane 63.
__device__ __forceinline__ float sum64_sc(float x) {
    x = dpp_add<0x111>(x);
    x = dpp_add<0x112>(x);
    x = dpp_add<0x114>(x);
    x = dpp_add<0x118>(x);
    x = dpp_add<0x142>(x);
    x = dpp_add<0x143>(x);
    return x;
}
__device__ __forceinline__ f32x2 lo2(f32x4 v) { return __builtin_shufflevector(v, v, 0, 1); }
__device__ __forceinline__ f32x2 hi2(f32x4 v) { return __builtin_shufflevector(v, v, 2, 3); }

// ---------- K0: feature -> bf16 ----------
__global__ void cvt_feat(const float* __restrict__ f, ushort_t* __restrict__ o, int n) {
    int i = blockIdx.x * blockDim.x + threadIdx.x;
    if (i < n) o[i] = f32_to_bf16(f[i]);
}

// ---------- K1: wqT[n][k] = bf16(wq[k][n]) ----------
__global__ void cvt_wqT(const float* __restrict__ wq, ushort_t* __restrict__ o) {
    __shared__ float tile[64][65];
    int bi = blockIdx.x, bj = blockIdx.y, tid = threadIdx.x;
    int c = tid & 63, r4 = tid >> 6;
    for (int it = 0; it < 16; ++it) {
        int r = it * 4 + r4;
        tile[r][c] = wq[(size_t)(bi * 64 + r) * D_ + bj * 64 + c];
    }
    __syncthreads();
    for (int it = 0; it < 16; ++it) {
        int r = it * 4 + r4;
        o[(size_t)(bj * 64 + r) * D_ + bi * 64 + c] = f32_to_bf16(tile[c][r]);
    }
}

// ---------- K2: qw = (featbf @ wqT^T + wq_b) * w2_w * log2(e)  (MFMA bf16) ----------
__global__ __launch_bounds__(256) void gemm_qw(
        const ushort_t* __restrict__ A, const ushort_t* __restrict__ BT,
        const float* __restrict__ wqb, const float* __restrict__ w2w,
        float* __restrict__ out) {
    const int K = 1024;
    __shared__ ushort_t Al[128][48];
    __shared__ ushort_t Bl[64][48];
    int tid = threadIdx.x;
    int lane = tid & 63, wv = tid >> 6;
    int wm = wv >> 1, wn = wv & 1;
    int m0 = blockIdx.x * 128, n0 = blockIdx.y * 64;
    int mrow = lane & 15, quad = lane >> 4;
    f32x4 acc[4][2] = {};
    for (int k0 = 0; k0 < K; k0 += 32) {
#pragma unroll
        for (int rep = 0; rep < 2; ++rep) {
            int idx = rep * 256 + tid;
            int r = idx >> 2, cp = (idx & 3) * 8;
            *(bf16x8*)&Al[r][cp] = *(const bf16x8*)&A[(size_t)(m0 + r) * K + k0 + cp];
        }
        {
            int r = tid >> 2, cp = (tid & 3) * 8;
            *(bf16x8*)&Bl[r][cp] = *(const bf16x8*)&BT[(size_t)(n0 + r) * K + k0 + cp];
        }
        __syncthreads();
        bf16x8 af[4], bfr[2];
#pragma unroll
        for (int ms = 0; ms < 4; ++ms) af[ms] = *(bf16x8*)&Al[wm * 64 + ms * 16 + mrow][quad * 8];
#pragma unroll
        for (int ns = 0; ns < 2; ++ns) bfr[ns] = *(bf16x8*)&Bl[wn * 32 + ns * 16 + mrow][quad * 8];
#pragma unroll
        for (int ms = 0; ms < 4; ++ms)
#pragma unroll
            for (int ns = 0; ns < 2; ++ns)
                acc[ms][ns] = __builtin_amdgcn_mfma_f32_16x16x32_bf16(af[ms], bfr[ns], acc[ms][ns], 0, 0, 0);
        __syncthreads();
    }
#pragma unroll
    for (int ns = 0; ns < 2; ++ns) {
        int n = n0 + wn * 32 + ns * 16 + mrow;
        float scale = w2w[n] * LOG2E, bias = wqb[n];
#pragma unroll
        for (int ms = 0; ms < 4; ++ms) {
#pragma unroll
            for (int r = 0; r < 4; ++r) {
                int m = m0 + wm * 64 + ms * 16 + quad * 4 + r;
                out[(size_t)m * D_ + n] = (acc[ms][ns][r] + bias) * scale;
            }
        }
    }
}

// ---------- K3: transpose first 64 feature rows: fT32/fTh/fTl [b][d][w] ----------
__global__ void featT_kernel(const float* __restrict__ feat, float* __restrict__ fT32,
                             ushort_t* __restrict__ fTh, ushort_t* __restrict__ fTl) {
    __shared__ float tile[64][65];
    int d0 = blockIdx.x * 64, b = blockIdx.y, tid = threadIdx.x;
    int c = tid & 63, r4 = tid >> 6;
#pragma unroll
    for (int it = 0; it < 16; ++it) {
        int r = it * 4 + r4;
        tile[r][c] = feat[((size_t)b * T_ + r) * D_ + d0 + c];
    }
    __syncthreads();
#pragma unroll
    for (int it = 0; it < 16; ++it) {
        int r = it * 4 + r4;
        float v = tile[c][r];
        size_t o = ((size_t)b * D_ + d0 + r) * 64 + c;
        fT32[o] = v;
        ushort_t h = f32_to_bf16(v);
        fTh[o] = h;
        fTl[o] = f32_to_bf16(v - bf16_to_f32(h));
    }
}

// ---------- K4: S0[b][t][w] = qw[b][t]·F0[b][w]  (fp32, stored as bf16 hi/lo) ----------
__global__ __launch_bounds__(256) void s0_gemm(
        const float* __restrict__ qw, const float* __restrict__ fT32,
        ushort_t* __restrict__ S0h, ushort_t* __restrict__ S0l) {
    __shared__ float As[64][17];
    __shared__ float Bs[16][65];
    int b = blockIdx.y;
    int t0 = 64 + blockIdx.x * 64;
    int tx = threadIdx.x & 15, ty = threadIdx.x >> 4;
    float acc[4][4] = {};
    for (int k0 = 0; k0 < D_; k0 += 16) {
#pragma unroll
        for (int i = 0; i < 4; ++i) {
            int idx = i * 256 + threadIdx.x;
            int r = idx >> 4, c = idx & 15;
            As[r][c] = qw[((size_t)b * T_ + t0 + r) * D_ + k0 + c];
        }
#pragma unroll
        for (int i = 0; i < 4; ++i) {
            int idx = i * 256 + threadIdx.x;
            int r = idx >> 6, c = idx & 63;
            Bs[r][c] = fT32[((size_t)b * D_ + k0 + r) * 64 + c];
        }
        __syncthreads();
#pragma unroll
        for (int kk = 0; kk < 16; ++kk)
#pragma unroll
            for (int i = 0; i < 4; ++i)
#pragma unroll
                for (int j = 0; j < 4; ++j)
                    acc[i][j] = fmaf(As[ty * 4 + i][kk], Bs[kk][tx * 4 + j], acc[i][j]);
        __syncthreads();
    }
#pragma unroll
    for (int i = 0; i < 4; ++i)
#pragma unroll
        for (int j = 0; j < 4; ++j) {
            float sc = acc[i][j];
            ushort_t h = f32_to_bf16(sc);
            size_t o = ((size_t)b * T_ + t0 + ty * 4 + i) * 64 + tx * 4 + j;
            S0h[o] = h;
            S0l[o] = f32_to_bf16(sc - bf16_to_f32(h));
        }
}

// ---------- K5: sequential core, 1 wave per batch ----------
// Lag-1 software pipeline: alpha-row LDS reads issued at step s are consumed
// by the bulk matvec at step s+1 (a full step of slack => no lgkm stall).
// The matvec's ULDS column write lands after this step's entering-row read;
// the one missing element is patched in registers (readlane, const lane) and
// the w-dot gets the matching algebraic correction.  Cross-step critical
// chain stays pure cross-lane: exp2 -> DPP reduce -> readlane -> rcp -> cnd.
__global__ __launch_bounds__(64, 1) void core_kernel(
        const ushort_t* __restrict__ S0h, const ushort_t* __restrict__ S0l,
        float* __restrict__ gamma) {
    const int b = blockIdx.x;
    const int lane = threadIdx.x;
    const int n16 = lane & 15, quad = lane >> 4;
    __shared__ float ULDS[64 * 67];          // Z: row=pos, col=slot
    __shared__ __align__(16) float ALPH[64 * 68];  // e matrix; col64 = rtot
    __shared__ __align__(16) float B1L[16 * 68];   // sub-block Gamma staging
    __shared__ ushort_t CH[64 * 72];         // C rows   [slot][basis]  bf16 hi
    __shared__ ushort_t CL[64 * 72];
    __shared__ ushort_t CWTh[64 * 72];       // C^T rows [basis][slot]  bf16 hi
    __shared__ ushort_t CWTl[64 * 72];

#pragma unroll
    for (int jj = 0; jj < 72; ++jj) {
        ushort_t idv = (jj == lane) ? (ushort_t)0x3F80 : (ushort_t)0;
        CH[lane * 72 + jj] = idv;  CL[lane * 72 + jj] = 0;
        CWTh[lane * 72 + jj] = idv; CWTl[lane * 72 + jj] = 0;
    }
    // single wave: DS pipe is in-order per wave; no barriers needed.

    f32x4 A[16];          // lag-1 alpha-row staging (raw e values, broadcast)
    float r_prev = 0.f;

#pragma unroll 1
    for (int p = 0; p < 31; ++p) {
        const int t0 = 64 + (p << 6);

        // ---- Lpre = S0sup @ C^T via split-bf16 MFMA -> ULDS ----
        // All global loads hoisted ahead of the MFMAs (one miss latency).
        {
            bf16x8 Bh[4][2], Blo[4][2];
#pragma unroll
            for (int nt = 0; nt < 4; ++nt)
#pragma unroll
                for (int kt = 0; kt < 2; ++kt) {
                    int a = (nt * 16 + n16) * 72 + kt * 32 + quad * 8;
                    Bh[nt][kt] = *(const bf16x8*)&CH[a];
                    Blo[nt][kt] = *(const bf16x8*)&CL[a];
                }
            bf16x8 SAh[4][2], SAl[4][2];
#pragma unroll
            for (int mt = 0; mt < 4; ++mt)
#pragma unroll
                for (int kt = 0; kt < 2; ++kt) {
                    size_t a = ((size_t)b * T_ + t0 + mt * 16 + n16) * 64 + kt * 32 + quad * 8;
                    SAh[mt][kt] = *(const bf16x8*)&S0h[a];
                    SAl[mt][kt] = *(const bf16x8*)&S0l[a];
                }
#pragma unroll
            for (int mt = 0; mt < 4; ++mt) {
                f32x4 acc[4] = {};
#pragma unroll
                for (int nt = 0; nt < 4; ++nt)
#pragma unroll
                    for (int kt = 0; kt < 2; ++kt) {
                        acc[nt] = __builtin_amdgcn_mfma_f32_16x16x32_bf16(SAh[mt][kt], Bh[nt][kt], acc[nt], 0, 0, 0);
                        acc[nt] = __builtin_amdgcn_mfma_f32_16x16x32_bf16(SAh[mt][kt], Blo[nt][kt], acc[nt], 0, 0, 0);
                        acc[nt] = __builtin_amdgcn_mfma_f32_16x16x32_bf16(SAl[mt][kt], Bh[nt][kt], acc[nt], 0, 0, 0);
                    }
#pragma unroll
                for (int nt = 0; nt < 4; ++nt)
#pragma unroll
                    for (int r = 0; r < 4; ++r)
                        ULDS[(mt * 16 + quad * 4 + r) * 67 + nt * 16 + n16] = acc[nt][r];
            }
        }

        // X (lane = time position, index = slot) as f32x2 pairs, constant-indexed
        f32x2 Xa2[8], Xb2[8], Xc2[8], Xd2[8];
#pragma unroll
        for (int l2 = 0; l2 < 8; ++l2) {
            Xa2[l2].x = ULDS[lane * 67 + 2 * l2];
            Xa2[l2].y = ULDS[lane * 67 + 2 * l2 + 1];
            Xb2[l2].x = ULDS[lane * 67 + 16 + 2 * l2];
            Xb2[l2].y = ULDS[lane * 67 + 16 + 2 * l2 + 1];
            Xc2[l2].x = ULDS[lane * 67 + 32 + 2 * l2];
            Xc2[l2].y = ULDS[lane * 67 + 32 + 2 * l2 + 1];
            Xd2[l2].x = ULDS[lane * 67 + 48 + 2 * l2];
            Xd2[l2].y = ULDS[lane * 67 + 48 + 2 * l2 + 1];
        }
        float row = ULDS[lane];           // Z row 0 (fresh from Lpre)
        float nxt = ULDS[67 + lane];      // Z row 1
        float Esave[16];

#pragma unroll 1
        for (int j = 0; j < 4; ++j) {
#pragma unroll
            for (int sl = 0; sl < 16; ++sl) {
                const int s = (j << 4) | sl;
                // entering-row read (row s+2); col s-1 not yet written -> reg patch below
                float nxt2v = 0.f;
                if (s <= 61) nxt2v = ULDS[(s + 2) * 67 + lane];
                float e = __builtin_amdgcn_exp2f(row);   // logits pre-scaled by log2e
                Esave[sl] = e;
                // ---- lag-1 bulk matvec for alpha_{s-1} (consumes A from last step) ----
                float u_new = 0.f;
                if (s >= 1 && s <= 61) {
                    f32x2 acc0 = {0.f, 0.f}, acc1 = {0.f, 0.f}, acc2 = {0.f, 0.f}, acc3 = {0.f, 0.f};
#pragma unroll
                    for (int i2 = 0; i2 < 4; ++i2) {
                        f32x4 aa = A[i2];
                        acc0 = __builtin_elementwise_fma(lo2(aa), Xa2[2 * i2], acc0);
                        acc1 = __builtin_elementwise_fma(hi2(aa), Xa2[2 * i2 + 1], acc1);
                        f32x4 ab = A[4 + i2];
                        acc2 = __builtin_elementwise_fma(lo2(ab), Xb2[2 * i2], acc2);
                        acc3 = __builtin_elementwise_fma(hi2(ab), Xb2[2 * i2 + 1], acc3);
                        f32x4 ac = A[8 + i2];
                        acc0 = __builtin_elementwise_fma(lo2(ac), Xc2[2 * i2], acc0);
                        acc1 = __builtin_elementwise_fma(hi2(ac), Xc2[2 * i2 + 1], acc1);
                        f32x4 ad = A[12 + i2];
                        acc2 = __builtin_elementwise_fma(lo2(ad), Xd2[2 * i2], acc2);
                        acc3 = __builtin_elementwise_fma(hi2(ad), Xd2[2 * i2 + 1], acc3);
                    }
                    f32x2 u2 = (acc0 + acc1) + (acc2 + acc3);
                    u_new = (u2.x + u2.y) * r_prev;
                    // X column update: col = s-1
                    if (sl >= 1) {
                        const int c = sl - 1;
                        if (j == 0)      { if (c & 1) Xa2[c >> 1].y = u_new; else Xa2[c >> 1].x = u_new; }
                        else if (j == 1) { if (c & 1) Xb2[c >> 1].y = u_new; else Xb2[c >> 1].x = u_new; }
                        else if (j == 2) { if (c & 1) Xc2[c >> 1].y = u_new; else Xc2[c >> 1].x = u_new; }
                        else             { if (c & 1) Xd2[c >> 1].y = u_new; else Xd2[c >> 1].x = u_new; }
                    } else {
                        // col = j*16 - 1: last slot of previous group
                        if (j == 1)      Xa2[7].y = u_new;
                        else if (j == 2) Xb2[7].y = u_new;
                        else             Xc2[7].y = u_new;   // j == 3
                    }
                    if (lane > s - 1) ULDS[lane * 67 + (s - 1)] = u_new;
                }
                // this step's e-row write, then issue next step's A reads behind it
                ALPH[s * 68 + lane] = e;
                if (s <= 60 && sl != 15) {
#pragma unroll
                    for (int i = 0; i < 16; ++i)
                        A[i] = *(const f32x4*)&ALPH[s * 68 + i * 4];
                }
                // cross-lane reduces
                f32x2 v; v.x = e; v.y = e * nxt;
                v = sum64_pair(v);
                float w_ = 0.f;
                if (s <= 61) w_ = sum64_sc(e * nxt2v);
                float tot = readlane_f(v.x, 63) + 1.f;   // + 2^0 zero-row
                float cs  = readlane_f(v.y, 63);
                float r = __builtin_amdgcn_rcpf(tot);
                if (s < 63) {
                    row = (lane == s) ? cs * r : nxt;
                    if (s <= 61) {
                        float wfix = readlane_f(w_, 63);
                        float nn = nxt2v;
                        if (s >= 1) {
                            float cnew = readlane_f(u_new, s + 2);          // u_{s-1}[s+2]
                            wfix += readlane_f(e, s - 1) * (cnew - readlane_f(nxt2v, s - 1));
                            nn = (lane == s - 1) ? cnew : nn;
                        }
                        nxt = (lane == s) ? wfix * r : nn;
                    } else {
                        nxt = 0.f;
                    }
                }
                if (lane == 0) ALPH[s * 68 + 64] = r;    // rtot for Gamma
                r_prev = r;
            }

            // ---- Gamma for sub-block j: B1 = A_J @ CW_preJ (MFMA) + pure-VALU sweep ----
            {
                const int J0 = j << 4;
                float rrow = ALPH[(J0 + n16) * 68 + 64];   // rtot of this lane's row
                bf16x8 Aah[2], Aal[2];
#pragma unroll
                for (int kt = 0; kt < 2; ++kt) {
                    float v[8];
                    *(float4*)&v[0] = *(const float4*)&ALPH[(J0 + n16) * 68 + kt * 32 + quad * 8];
                    *(float4*)&v[4] = *(const float4*)&ALPH[(J0 + n16) * 68 + kt * 32 + quad * 8 + 4];
                    bf16x8 h, l;
#pragma unroll
                    for (int i = 0; i < 8; ++i) {
                        float val = v[i] * rrow;           // alpha = e * rtot
                        ushort_t hh = f32_to_bf16(val);
                        h[i] = (short)hh;
                        l[i] = (short)f32_to_bf16(val - bf16_to_f32(hh));
                    }
                    Aah[kt] = h; Aal[kt] = l;
                }
#pragma unroll
                for (int nt = 0; nt < 4; ++nt) {
                    f32x4 a = {};
#pragma unroll
                    for (int kt = 0; kt < 2; ++kt) {
                        bf16x8 bh = *(const bf16x8*)&CWTh[(nt * 16 + n16) * 72 + kt * 32 + quad * 8];
                        bf16x8 bl = *(const bf16x8*)&CWTl[(nt * 16 + n16) * 72 + kt * 32 + quad * 8];
                        a = __builtin_amdgcn_mfma_f32_16x16x32_bf16(Aah[kt], bh, a, 0, 0, 0);
                        a = __builtin_amdgcn_mfma_f32_16x16x32_bf16(Aah[kt], bl, a, 0, 0, 0);
                        a = __builtin_amdgcn_mfma_f32_16x16x32_bf16(Aal[kt], bh, a, 0, 0, 0);
                    }
#pragma unroll
                    for (int r = 0; r < 4; ++r)
                        B1L[(quad * 4 + r) * 68 + nt * 16 + n16] = a[r];
                }
                // hoisted sweep inputs (all LDS latency off the D-chain)
                float b1v[16], ov[16], rr[16];
#pragma unroll
                for (int s2 = 0; s2 < 16; ++s2) {
                    b1v[s2] = B1L[s2 * 68 + lane];
                    ov[s2] = bf16_to_f32(CH[(J0 + s2) * 72 + lane]) + bf16_to_f32(CL[(J0 + s2) * 72 + lane]);
                    rr[s2] = ALPH[(J0 + s2) * 68 + 64];
                }
                // triangular correction sweep (lane = basis column), pure VALU
                float D[16];
#pragma unroll
                for (int s2 = 0; s2 < 16; ++s2) {
                    float corr = 0.f;
#pragma unroll
                    for (int c = 0; c < 16; ++c)
                        if (c < s2)
                            corr = fmaf(readlane_f(Esave[s2], J0 + c), D[c], corr);
                    float g = fmaf(rr[s2], corr, b1v[s2]);
                    const int slot = J0 + s2;
                    D[s2] = g - ov[s2];
                    gamma[((size_t)b * T_ + t0 + slot) * 64 + lane] = g;
                    ushort_t gh = f32_to_bf16(g);
                    ushort_t gl2 = f32_to_bf16(g - bf16_to_f32(gh));
                    CH[slot * 72 + lane] = gh;  CL[slot * 72 + lane] = gl2;
                    CWTh[lane * 72 + slot] = gh; CWTl[lane * 72 + slot] = gl2;
                }
            }
            // deferred A-read issue for the sub-block's last step (row J0+15)
            if (j < 3) {
                const int s15 = (j << 4) | 15;
#pragma unroll
                for (int i = 0; i < 16; ++i)
                    A[i] = *(const f32x4*)&ALPH[s15 * 68 + i * 4];
            }
        }
    }
}

// ---------- K6: prologue rows 0..63: out = LN(tanh(f)*f + f) ----------
__global__ __launch_bounds__(256) void prologue_kernel(
        const float* __restrict__ feat, float* __restrict__ out,
        const float* __restrict__ lng, const float* __restrict__ lnb) {
    int b = blockIdx.y, t = blockIdx.x, tid = threadIdx.x;
    __shared__ float red[4][2];
    size_t base = ((size_t)b * T_ + t) * D_;
    float4 f4 = *(const float4*)&feat[base + tid * 4];
    float4 y;
    y.x = tanh_fast(f4.x) * f4.x + f4.x;
    y.y = tanh_fast(f4.y) * f4.y + f4.y;
    y.z = tanh_fast(f4.z) * f4.z + f4.z;
    y.w = tanh_fast(f4.w) * f4.w + f4.w;
    float s1 = y.x + y.y + y.z + y.w;
    float s2 = y.x * y.x + y.y * y.y + y.z * y.z + y.w * y.w;
#pragma unroll
    for (int m = 1; m < 64; m <<= 1) { s1 += __shfl_xor(s1, m, 64); s2 += __shfl_xor(s2, m, 64); }
    if ((tid & 63) == 0) { red[tid >> 6][0] = s1; red[tid >> 6][1] = s2; }
    __syncthreads();
    float mu = (red[0][0] + red[1][0] + red[2][0] + red[3][0]) * (1.f / D_);
    float m2 = (red[0][1] + red[1][1] + red[2][1] + red[3][1]) * (1.f / D_);
    float rv = rsqrtf(fmaxf(m2 - mu * mu, 0.f) + LN_EPS);
    float4 g4 = *(const float4*)&lng[tid * 4];
    float4 b4 = *(const float4*)&lnb[tid * 4];
    float4 o;
    o.x = (y.x - mu) * rv * g4.x + b4.x;
    o.y = (y.y - mu) * rv * g4.y + b4.y;
    o.z = (y.z - mu) * rv * g4.z + b4.z;
    o.w = (y.w - mu) * rv * g4.w + b4.w;
    *(float4*)&out[base + tid * 4] = o;
}

// ---------- K7: V = Γ @ F0 (split-bf16 MFMA) fused with gate + LayerNorm ----------
__global__ __launch_bounds__(256) void final_kernel(
        const float* __restrict__ gamma, const ushort_t* __restrict__ fTh,
        const ushort_t* __restrict__ fTl, const float* __restrict__ feat,
        const float* __restrict__ lng, const float* __restrict__ lnb,
        float* __restrict__ out) {
    const int b = blockIdx.y;
    const int t0 = 64 + blockIdx.x * 16;
    const int tid = threadIdx.x, lane = tid & 63, wv = tid >> 6;
    const int n16 = lane & 15, quad = lane >> 4;
    __shared__ float wsum[4][16][2];
    __shared__ float lnp[16][2];

    bf16x8 Ah[2], Alo[2];
    {
        const float* gr = &gamma[((size_t)b * T_ + t0 + n16) * 64];
#pragma unroll
        for (int kt = 0; kt < 2; ++kt) {
            float g[8];
            *(float4*)&g[0] = *(const float4*)&gr[kt * 32 + quad * 8];
            *(float4*)&g[4] = *(const float4*)&gr[kt * 32 + quad * 8 + 4];
            bf16x8 h, l;
#pragma unroll
            for (int i = 0; i < 8; ++i) {
                ushort_t hh = f32_to_bf16(g[i]);
                h[i] = (short)hh;
                l[i] = (short)f32_to_bf16(g[i] - bf16_to_f32(hh));
            }
            Ah[kt] = h; Alo[kt] = l;
        }
    }
    f32x4 acc[16];
#pragma unroll
    for (int j = 0; j < 16; ++j) {
        const int d = wv * 256 + j * 16 + n16;
        const ushort_t* fr = &fTh[((size_t)b * D_ + d) * 64];
        const ushort_t* fr2 = &fTl[((size_t)b * D_ + d) * 64];
        f32x4 a = {0.f, 0.f, 0.f, 0.f};
#pragma unroll
        for (int kt = 0; kt < 2; ++kt) {
            bf16x8 bh = *(const bf16x8*)&fr[kt * 32 + quad * 8];
            bf16x8 bl = *(const bf16x8*)&fr2[kt * 32 + quad * 8];
            a = __builtin_amdgcn_mfma_f32_16x16x32_bf16(Ah[kt], bh, a, 0, 0, 0);
            a = __builtin_amdgcn_mfma_f32_16x16x32_bf16(Ah[kt], bl, a, 0, 0, 0);
            a = __builtin_amdgcn_mfma_f32_16x16x32_bf16(Alo[kt], bh, a, 0, 0, 0);
        }
        acc[j] = a;
    }
    float s1[4] = {0.f, 0.f, 0.f, 0.f}, s2[4] = {0.f, 0.f, 0.f, 0.f};
#pragma unroll
    for (int j = 0; j < 16; ++j) {
        const int d = wv * 256 + j * 16 + n16;
#pragma unroll
        for (int r = 0; r < 4; ++r) {
            float f = feat[((size_t)b * T_ + t0 + quad * 4 + r) * D_ + d];
            float y = tanh_fast(acc[j][r]) * f + f;
            acc[j][r] = y;
            s1[r] += y;
            s2[r] += y * y;
        }
    }
#pragma unroll
    for (int m = 1; m < 16; m <<= 1)
#pragma unroll
        for (int r = 0; r < 4; ++r) { s1[r] += __shfl_xor(s1[r], m, 64); s2[r] += __shfl_xor(s2[r], m, 64); }
    if (n16 == 0) {
#pragma unroll
        for (int r = 0; r < 4; ++r) { wsum[wv][quad * 4 + r][0] = s1[r]; wsum[wv][quad * 4 + r][1] = s2[r]; }
    }
    __syncthreads();
    if (tid < 16) {
        float a = 0.f, c = 0.f;
#pragma unroll
        for (int w2 = 0; w2 < 4; ++w2) { a += wsum[w2][tid][0]; c += wsum[w2][tid][1]; }
        float mu = a * (1.f / D_);
        float var = c * (1.f / D_) - mu * mu;
        lnp[tid][0] = mu;
        lnp[tid][1] = rsqrtf(fmaxf(var, 0.f) + LN_EPS);
    }
    __syncthreads();
#pragma unroll
    for (int j = 0; j < 16; ++j) {
        const int d = wv * 256 + j * 16 + n16;
        float gd = lng[d], bd = lnb[d];
#pragma unroll
        for (int r = 0; r < 4; ++r) {
            int row = quad * 4 + r;
            out[((size_t)b * T_ + t0 + row) * D_ + d] = (acc[j][r] - lnp[row][0]) * lnp[row][1] * gd + bd;
        }
    }
}

extern "C" void kernel_launch(void* const* d_in, const int* in_sizes, int n_in,
                              void* d_out, int out_size, void* d_ws, size_t ws_size,
                              hipStream_t stream) {
    const float* feature = (const float*)d_in[0];
    const float* wq_w    = (const float*)d_in[1];
    const float* wq_b    = (const float*)d_in[2];
    const float* w2_w    = (const float*)d_in[3];
    // d_in[4] = w2_b: softmax-invariant, unused
    const float* ln_g    = (const float*)d_in[5];
    const float* ln_b    = (const float*)d_in[6];
    float* out = (float*)d_out;

    uint8_t* ws = (uint8_t*)d_ws;
    // phase-1 regions
    ushort_t* featbf = (ushort_t*)(ws);                       // 32 MB (dead after gemm_qw)
    ushort_t* wqT    = (ushort_t*)(ws + 32u * 1024 * 1024);   // 2 MB
    // phase-2 regions (alias featbf space)
    float*    gamma = (float*)(ws);                           // 4 MB
    ushort_t* S0h   = (ushort_t*)(ws + 4u * 1024 * 1024);     // 2 MB
    ushort_t* S0l   = (ushort_t*)(ws + 6u * 1024 * 1024);     // 2 MB
    float*    fT32  = (float*)(ws + 8u * 1024 * 1024);        // 2 MB
    ushort_t* fTh   = (ushort_t*)(ws + 10u * 1024 * 1024);    // 1 MB
    ushort_t* fTl   = (ushort_t*)(ws + 11u * 1024 * 1024);    // 1 MB

    const int ntot = B_ * T_ * D_;
    cvt_feat<<<(ntot + 255) / 256, 256, 0, stream>>>(feature, featbf, ntot);
    cvt_wqT<<<dim3(16, 16), 256, 0, stream>>>(wq_w, wqT);
    gemm_qw<<<dim3(128, 16), 256, 0, stream>>>(featbf, wqT, wq_b, w2_w, out);
    featT_kernel<<<dim3(16, 8), 256, 0, stream>>>(feature, fT32, fTh, fTl);
    s0_gemm<<<dim3(31, 8), 256, 0, stream>>>(out, fT32, S0h, S0l);
    core_kernel<<<8, 64, 0, stream>>>(S0h, S0l, gamma);
    prologue_kernel<<<dim3(64, 8), 256, 0, stream>>>(feature, out, ln_g, ln_b);
    final_kernel<<<dim3(124, 8), 256, 0, stream>>>(gamma, fTh, fTl, feature, ln_g, ln_b, out);
}

// Round 5
// 1410.206 us; speedup vs baseline: 1.0097x; 1.0097x over previous
//
#include <hip/hip_runtime.h>
#include <hip/hip_bf16.h>

#define B_ 8
#define T_ 2048
#define D_ 1024
#define W_ 64
#define LN_EPS 1e-5f
#define LOG2E 1.4426950408889634f

typedef __attribute__((ext_vector_type(8))) short bf16x8;
typedef __attribute__((ext_vector_type(4))) float f32x4;
typedef __attribute__((ext_vector_type(2))) float f32x2;
typedef unsigned short ushort_t;

__device__ __forceinline__ ushort_t f32_to_bf16(float f) {
    union { float ff; unsigned u; } c; c.ff = f;
    unsigned r = (c.u + 0x7fffu + ((c.u >> 16) & 1u)) >> 16;
    return (ushort_t)r;
}
__device__ __forceinline__ float bf16_to_f32(ushort_t h) {
    union { unsigned u; float f; } c; c.u = ((unsigned)h) << 16; return c.f;
}
__device__ __forceinline__ float tanh_fast(float x) {
    float xx = fminf(fmaxf(x, -20.f), 20.f);
    float e = __expf(2.f * xx);
    return 1.f - 2.f / (e + 1.f);
}
__device__ __forceinline__ float readlane_f(float v, int l) {
    return __int_as_float(__builtin_amdgcn_readlane(__float_as_int(v), l));
}
// DPP-based add with immediate control (template => constant integer)
template <int CTRL>
__device__ __forceinline__ float dpp_add(float x) {
    int y = __builtin_amdgcn_update_dpp(0, __float_as_int(x), CTRL, 0xf, 0xf, true);
    return x + __int_as_float(y);
}
// Packed pair reduction: one DPP chain reduces both components.
template <int CTRL>
__device__ __forceinline__ f32x2 pk_dpp_add(f32x2 v) {
    f32x2 t;
    t.x = __int_as_float(__builtin_amdgcn_update_dpp(0, __float_as_int(v.x), CTRL, 0xf, 0xf, true));
    t.y = __int_as_float(__builtin_amdgcn_update_dpp(0, __float_as_int(v.y), CTRL, 0xf, 0xf, true));
    return v + t;
}
__device__ __forceinline__ f32x2 sum64_pair(f32x2 v) {
    v = pk_dpp_add<0x111>(v);  // row_shr:1
    v = pk_dpp_add<0x112>(v);  // row_shr:2
    v = pk_dpp_add<0x114>(v);  // row_shr:4
    v = pk_dpp_add<0x118>(v);  // row_shr:8
    v = pk_dpp_add<0x142>(v);  // row_bcast:15
    v = pk_dpp_add<0x143>(v);  // row_bcast:31 -> lane63 = totals
    return v;
}
// Scalar 64-lane sum; total lands in lane 63.
__device__ __forceinline__ float sum64_sc(float x) {
    x = dpp_add<0x111>(x);
    x = dpp_add<0x112>(x);
    x = dpp_add<0x114>(x);
    x = dpp_add<0x118>(x);
    x = dpp_add<0x142>(x);
    x = dpp_add<0x143>(x);
    return x;
}
__device__ __forceinline__ f32x2 lo2(f32x4 v) { return __builtin_shufflevector(v, v, 0, 1); }
__device__ __forceinline__ f32x2 hi2(f32x4 v) { return __builtin_shufflevector(v, v, 2, 3); }

// ---------- K0: feature -> bf16 ----------
__global__ void cvt_feat(const float* __restrict__ f, ushort_t* __restrict__ o, int n) {
    int i = blockIdx.x * blockDim.x + threadIdx.x;
    if (i < n) o[i] = f32_to_bf16(f[i]);
}

// ---------- K1: wqT[n][k] = bf16(wq[k][n]) ----------
__global__ void cvt_wqT(const float* __restrict__ wq, ushort_t* __restrict__ o) {
    __shared__ float tile[64][65];
    int bi = blockIdx.x, bj = blockIdx.y, tid = threadIdx.x;
    int c = tid & 63, r4 = tid >> 6;
    for (int it = 0; it < 16; ++it) {
        int r = it * 4 + r4;
        tile[r][c] = wq[(size_t)(bi * 64 + r) * D_ + bj * 64 + c];
    }
    __syncthreads();
    for (int it = 0; it < 16; ++it) {
        int r = it * 4 + r4;
        o[(size_t)(bj * 64 + r) * D_ + bi * 64 + c] = f32_to_bf16(tile[c][r]);
    }
}

// ---------- K2: qw = (featbf @ wqT^T + wq_b) * w2_w * log2(e)  (MFMA bf16) ----------
__global__ __launch_bounds__(256) void gemm_qw(
        const ushort_t* __restrict__ A, const ushort_t* __restrict__ BT,
        const float* __restrict__ wqb, const float* __restrict__ w2w,
        float* __restrict__ out) {
    const int K = 1024;
    __shared__ ushort_t Al[128][48];
    __shared__ ushort_t Bl[64][48];
    int tid = threadIdx.x;
    int lane = tid & 63, wv = tid >> 6;
    int wm = wv >> 1, wn = wv & 1;
    int m0 = blockIdx.x * 128, n0 = blockIdx.y * 64;
    int mrow = lane & 15, quad = lane >> 4;
    f32x4 acc[4][2] = {};
    for (int k0 = 0; k0 < K; k0 += 32) {
#pragma unroll
        for (int rep = 0; rep < 2; ++rep) {
            int idx = rep * 256 + tid;
            int r = idx >> 2, cp = (idx & 3) * 8;
            *(bf16x8*)&Al[r][cp] = *(const bf16x8*)&A[(size_t)(m0 + r) * K + k0 + cp];
        }
        {
            int r = tid >> 2, cp = (tid & 3) * 8;
            *(bf16x8*)&Bl[r][cp] = *(const bf16x8*)&BT[(size_t)(n0 + r) * K + k0 + cp];
        }
        __syncthreads();
        bf16x8 af[4], bfr[2];
#pragma unroll
        for (int ms = 0; ms < 4; ++ms) af[ms] = *(bf16x8*)&Al[wm * 64 + ms * 16 + mrow][quad * 8];
#pragma unroll
        for (int ns = 0; ns < 2; ++ns) bfr[ns] = *(bf16x8*)&Bl[wn * 32 + ns * 16 + mrow][quad * 8];
#pragma unroll
        for (int ms = 0; ms < 4; ++ms)
#pragma unroll
            for (int ns = 0; ns < 2; ++ns)
                acc[ms][ns] = __builtin_amdgcn_mfma_f32_16x16x32_bf16(af[ms], bfr[ns], acc[ms][ns], 0, 0, 0);
        __syncthreads();
    }
#pragma unroll
    for (int ns = 0; ns < 2; ++ns) {
        int n = n0 + wn * 32 + ns * 16 + mrow;
        float scale = w2w[n] * LOG2E, bias = wqb[n];
#pragma unroll
        for (int ms = 0; ms < 4; ++ms) {
#pragma unroll
            for (int r = 0; r < 4; ++r) {
                int m = m0 + wm * 64 + ms * 16 + quad * 4 + r;
                out[(size_t)m * D_ + n] = (acc[ms][ns][r] + bias) * scale;
            }
        }
    }
}

// ---------- K3: transpose first 64 feature rows: fT32/fTh/fTl [b][d][w] ----------
__global__ void featT_kernel(const float* __restrict__ feat, float* __restrict__ fT32,
                             ushort_t* __restrict__ fTh, ushort_t* __restrict__ fTl) {
    __shared__ float tile[64][65];
    int d0 = blockIdx.x * 64, b = blockIdx.y, tid = threadIdx.x;
    int c = tid & 63, r4 = tid >> 6;
#pragma unroll
    for (int it = 0; it < 16; ++it) {
        int r = it * 4 + r4;
        tile[r][c] = feat[((size_t)b * T_ + r) * D_ + d0 + c];
    }
    __syncthreads();
#pragma unroll
    for (int it = 0; it < 16; ++it) {
        int r = it * 4 + r4;
        float v = tile[c][r];
        size_t o = ((size_t)b * D_ + d0 + r) * 64 + c;
        fT32[o] = v;
        ushort_t h = f32_to_bf16(v);
        fTh[o] = h;
        fTl[o] = f32_to_bf16(v - bf16_to_f32(h));
    }
}

// ---------- K4: S0[b][t][w] = qw[b][t]·F0[b][w]  (fp32, stored as bf16 hi/lo) ----------
__global__ __launch_bounds__(256) void s0_gemm(
        const float* __restrict__ qw, const float* __restrict__ fT32,
        ushort_t* __restrict__ S0h, ushort_t* __restrict__ S0l) {
    __shared__ float As[64][17];
    __shared__ float Bs[16][65];
    int b = blockIdx.y;
    int t0 = 64 + blockIdx.x * 64;
    int tx = threadIdx.x & 15, ty = threadIdx.x >> 4;
    float acc[4][4] = {};
    for (int k0 = 0; k0 < D_; k0 += 16) {
#pragma unroll
        for (int i = 0; i < 4; ++i) {
            int idx = i * 256 + threadIdx.x;
            int r = idx >> 4, c = idx & 15;
            As[r][c] = qw[((size_t)b * T_ + t0 + r) * D_ + k0 + c];
        }
#pragma unroll
        for (int i = 0; i < 4; ++i) {
            int idx = i * 256 + threadIdx.x;
            int r = idx >> 6, c = idx & 63;
            Bs[r][c] = fT32[((size_t)b * D_ + k0 + r) * 64 + c];
        }
        __syncthreads();
#pragma unroll
        for (int kk = 0; kk < 16; ++kk)
#pragma unroll
            for (int i = 0; i < 4; ++i)
#pragma unroll
                for (int j = 0; j < 4; ++j)
                    acc[i][j] = fmaf(As[ty * 4 + i][kk], Bs[kk][tx * 4 + j], acc[i][j]);
        __syncthreads();
    }
#pragma unroll
    for (int i = 0; i < 4; ++i)
#pragma unroll
        for (int j = 0; j < 4; ++j) {
            float sc = acc[i][j];
            ushort_t h = f32_to_bf16(sc);
            size_t o = ((size_t)b * T_ + t0 + ty * 4 + i) * 64 + tx * 4 + j;
            S0h[o] = h;
            S0l[o] = f32_to_bf16(sc - bf16_to_f32(h));
        }
}

// ---------- K5: sequential core, 1 wave per batch ----------
// Lag-1 software pipeline with COMPILER-PINNED schedule: sched_barrier(0)
// fences keep (a) the entering-row read at the top of the step and (b) the
// next-step alpha-row reads issued a full step before their use, so the
// scheduler cannot sink the ds_reads to just-before-use (which would
// recreate the write->read->use roundtrip on the serial chain).
__global__ __launch_bounds__(64, 1) void core_kernel(
        const ushort_t* __restrict__ S0h, const ushort_t* __restrict__ S0l,
        float* __restrict__ gamma) {
    const int b = blockIdx.x;
    const int lane = threadIdx.x;
    const int n16 = lane & 15, quad = lane >> 4;
    __shared__ float ULDS[64 * 67];          // Z: row=pos, col=slot
    __shared__ __align__(16) float ALPH[64 * 68];  // e matrix; col64 = rtot
    __shared__ __align__(16) float B1L[16 * 68];   // sub-block Gamma staging
    __shared__ ushort_t CH[64 * 72];         // C rows   [slot][basis]  bf16 hi
    __shared__ ushort_t CL[64 * 72];
    __shared__ ushort_t CWTh[64 * 72];       // C^T rows [basis][slot]  bf16 hi
    __shared__ ushort_t CWTl[64 * 72];

#pragma unroll
    for (int jj = 0; jj < 72; ++jj) {
        ushort_t idv = (jj == lane) ? (ushort_t)0x3F80 : (ushort_t)0;
        CH[lane * 72 + jj] = idv;  CL[lane * 72 + jj] = 0;
        CWTh[lane * 72 + jj] = idv; CWTl[lane * 72 + jj] = 0;
    }
    // single wave: DS pipe is in-order per wave; no barriers needed.

    f32x4 A[16];          // lag-1 alpha-row staging (raw e values, broadcast)
    float r_prev = 0.f;

#pragma unroll 1
    for (int p = 0; p < 31; ++p) {
        const int t0 = 64 + (p << 6);

        // ---- Lpre = S0sup @ C^T via split-bf16 MFMA -> ULDS ----
        {
            bf16x8 Bh[4][2], Blo[4][2];
#pragma unroll
            for (int nt = 0; nt < 4; ++nt)
#pragma unroll
                for (int kt = 0; kt < 2; ++kt) {
                    int a = (nt * 16 + n16) * 72 + kt * 32 + quad * 8;
                    Bh[nt][kt] = *(const bf16x8*)&CH[a];
                    Blo[nt][kt] = *(const bf16x8*)&CL[a];
                }
            bf16x8 SAh[4][2], SAl[4][2];
#pragma unroll
            for (int mt = 0; mt < 4; ++mt)
#pragma unroll
                for (int kt = 0; kt < 2; ++kt) {
                    size_t a = ((size_t)b * T_ + t0 + mt * 16 + n16) * 64 + kt * 32 + quad * 8;
                    SAh[mt][kt] = *(const bf16x8*)&S0h[a];
                    SAl[mt][kt] = *(const bf16x8*)&S0l[a];
                }
#pragma unroll
            for (int mt = 0; mt < 4; ++mt) {
                f32x4 acc[4] = {};
#pragma unroll
                for (int nt = 0; nt < 4; ++nt)
#pragma unroll
                    for (int kt = 0; kt < 2; ++kt) {
                        acc[nt] = __builtin_amdgcn_mfma_f32_16x16x32_bf16(SAh[mt][kt], Bh[nt][kt], acc[nt], 0, 0, 0);
                        acc[nt] = __builtin_amdgcn_mfma_f32_16x16x32_bf16(SAh[mt][kt], Blo[nt][kt], acc[nt], 0, 0, 0);
                        acc[nt] = __builtin_amdgcn_mfma_f32_16x16x32_bf16(SAl[mt][kt], Bh[nt][kt], acc[nt], 0, 0, 0);
                    }
#pragma unroll
                for (int nt = 0; nt < 4; ++nt)
#pragma unroll
                    for (int r = 0; r < 4; ++r)
                        ULDS[(mt * 16 + quad * 4 + r) * 67 + nt * 16 + n16] = acc[nt][r];
            }
        }

        // X (lane = time position, index = slot) as f32x2 pairs, constant-indexed
        f32x2 Xa2[8], Xb2[8], Xc2[8], Xd2[8];
#pragma unroll
        for (int l2 = 0; l2 < 8; ++l2) {
            Xa2[l2].x = ULDS[lane * 67 + 2 * l2];
            Xa2[l2].y = ULDS[lane * 67 + 2 * l2 + 1];
            Xb2[l2].x = ULDS[lane * 67 + 16 + 2 * l2];
            Xb2[l2].y = ULDS[lane * 67 + 16 + 2 * l2 + 1];
            Xc2[l2].x = ULDS[lane * 67 + 32 + 2 * l2];
            Xc2[l2].y = ULDS[lane * 67 + 32 + 2 * l2 + 1];
            Xd2[l2].x = ULDS[lane * 67 + 48 + 2 * l2];
            Xd2[l2].y = ULDS[lane * 67 + 48 + 2 * l2 + 1];
        }
        float row = ULDS[lane];           // Z row 0 (fresh from Lpre)
        float nxt = ULDS[67 + lane];      // Z row 1
        float Esave[16];

#pragma unroll 1
        for (int j = 0; j < 4; ++j) {
#pragma unroll
            for (int sl = 0; sl < 16; ++sl) {
                const int s = (j << 4) | sl;
                // entering-row read (row s+2); col s-1 not yet written -> reg patch below
                float nxt2v = 0.f;
                if (s <= 61) nxt2v = ULDS[(s + 2) * 67 + lane];
                __builtin_amdgcn_sched_barrier(0);   // pin the read at step top
                float e = __builtin_amdgcn_exp2f(row);   // logits pre-scaled by log2e
                Esave[sl] = e;
                // ---- lag-1 bulk matvec for alpha_{s-1} (consumes A from last step) ----
                float u_new = 0.f;
                if (s >= 1 && s <= 61) {
                    f32x2 acc0 = {0.f, 0.f}, acc1 = {0.f, 0.f}, acc2 = {0.f, 0.f}, acc3 = {0.f, 0.f};
#pragma unroll
                    for (int i2 = 0; i2 < 4; ++i2) {
                        f32x4 aa = A[i2];
                        acc0 = __builtin_elementwise_fma(lo2(aa), Xa2[2 * i2], acc0);
                        acc1 = __builtin_elementwise_fma(hi2(aa), Xa2[2 * i2 + 1], acc1);
                        f32x4 ab = A[4 + i2];
                        acc2 = __builtin_elementwise_fma(lo2(ab), Xb2[2 * i2], acc2);
                        acc3 = __builtin_elementwise_fma(hi2(ab), Xb2[2 * i2 + 1], acc3);
                        f32x4 ac = A[8 + i2];
                        acc0 = __builtin_elementwise_fma(lo2(ac), Xc2[2 * i2], acc0);
                        acc1 = __builtin_elementwise_fma(hi2(ac), Xc2[2 * i2 + 1], acc1);
                        f32x4 ad = A[12 + i2];
                        acc2 = __builtin_elementwise_fma(lo2(ad), Xd2[2 * i2], acc2);
                        acc3 = __builtin_elementwise_fma(hi2(ad), Xd2[2 * i2 + 1], acc3);
                    }
                    f32x2 u2 = (acc0 + acc1) + (acc2 + acc3);
                    u_new = (u2.x + u2.y) * r_prev;
                    // X column update: col = s-1
                    if (sl >= 1) {
                        const int c = sl - 1;
                        if (j == 0)      { if (c & 1) Xa2[c >> 1].y = u_new; else Xa2[c >> 1].x = u_new; }
                        else if (j == 1) { if (c & 1) Xb2[c >> 1].y = u_new; else Xb2[c >> 1].x = u_new; }
                        else if (j == 2) { if (c & 1) Xc2[c >> 1].y = u_new; else Xc2[c >> 1].x = u_new; }
                        else             { if (c & 1) Xd2[c >> 1].y = u_new; else Xd2[c >> 1].x = u_new; }
                    } else {
                        // col = j*16 - 1: last slot of previous group
                        if (j == 1)      Xa2[7].y = u_new;
                        else if (j == 2) Xb2[7].y = u_new;
                        else             Xc2[7].y = u_new;   // j == 3
                    }
                    if (lane > s - 1) ULDS[lane * 67 + (s - 1)] = u_new;
                }
                // this step's e-row write, then issue next step's A reads behind it
                ALPH[s * 68 + lane] = e;
                if (s <= 60 && sl != 15) {
#pragma unroll
                    for (int i = 0; i < 16; ++i)
                        A[i] = *(const f32x4*)&ALPH[s * 68 + i * 4];
                }
                __builtin_amdgcn_sched_barrier(0);   // pin A-read issue a full step early
                // cross-lane reduces
                f32x2 v; v.x = e; v.y = e * nxt;
                v = sum64_pair(v);
                float w_ = 0.f;
                if (s <= 61) w_ = sum64_sc(e * nxt2v);
                float tot = readlane_f(v.x, 63) + 1.f;   // + 2^0 zero-row
                float cs  = readlane_f(v.y, 63);
                float r = __builtin_amdgcn_rcpf(tot);
                if (s < 63) {
                    row = (lane == s) ? cs * r : nxt;
                    if (s <= 61) {
                        float wfix = readlane_f(w_, 63);
                        float nn = nxt2v;
                        if (s >= 1) {
                            float cnew = readlane_f(u_new, s + 2);          // u_{s-1}[s+2]
                            wfix += readlane_f(e, s - 1) * (cnew - readlane_f(nxt2v, s - 1));
                            nn = (lane == s - 1) ? cnew : nn;
                        }
                        nxt = (lane == s) ? wfix * r : nn;
                    } else {
                        nxt = 0.f;
                    }
                }
                if (lane == 0) ALPH[s * 68 + 64] = r;    // rtot for Gamma
                r_prev = r;
            }

            // ---- Gamma for sub-block j: B1 = A_J @ CW_preJ (MFMA) + pure-VALU sweep ----
            {
                const int J0 = j << 4;
                float rrow = ALPH[(J0 + n16) * 68 + 64];   // rtot of this lane's row
                bf16x8 Aah[2], Aal[2];
#pragma unroll
                for (int kt = 0; kt < 2; ++kt) {
                    float v[8];
                    *(float4*)&v[0] = *(const float4*)&ALPH[(J0 + n16) * 68 + kt * 32 + quad * 8];
                    *(float4*)&v[4] = *(const float4*)&ALPH[(J0 + n16) * 68 + kt * 32 + quad * 8 + 4];
                    bf16x8 h, l;
#pragma unroll
                    for (int i = 0; i < 8; ++i) {
                        float val = v[i] * rrow;           // alpha = e * rtot
                        ushort_t hh = f32_to_bf16(val);
                        h[i] = (short)hh;
                        l[i] = (short)f32_to_bf16(val - bf16_to_f32(hh));
                    }
                    Aah[kt] = h; Aal[kt] = l;
                }
#pragma unroll
                for (int nt = 0; nt < 4; ++nt) {
                    f32x4 a = {};
#pragma unroll
                    for (int kt = 0; kt < 2; ++kt) {
                        bf16x8 bh = *(const bf16x8*)&CWTh[(nt * 16 + n16) * 72 + kt * 32 + quad * 8];
                        bf16x8 bl = *(const bf16x8*)&CWTl[(nt * 16 + n16) * 72 + kt * 32 + quad * 8];
                        a = __builtin_amdgcn_mfma_f32_16x16x32_bf16(Aah[kt], bh, a, 0, 0, 0);
                        a = __builtin_amdgcn_mfma_f32_16x16x32_bf16(Aah[kt], bl, a, 0, 0, 0);
                        a = __builtin_amdgcn_mfma_f32_16x16x32_bf16(Aal[kt], bh, a, 0, 0, 0);
                    }
#pragma unroll
                    for (int r = 0; r < 4; ++r)
                        B1L[(quad * 4 + r) * 68 + nt * 16 + n16] = a[r];
                }
                // hoisted sweep inputs (all LDS latency off the D-chain)
                float b1v[16], ov[16], rr[16];
#pragma unroll
                for (int s2 = 0; s2 < 16; ++s2) {
                    b1v[s2] = B1L[s2 * 68 + lane];
                    ov[s2] = bf16_to_f32(CH[(J0 + s2) * 72 + lane]) + bf16_to_f32(CL[(J0 + s2) * 72 + lane]);
                    rr[s2] = ALPH[(J0 + s2) * 68 + 64];
                }
                // triangular correction sweep (lane = basis column), pure VALU
                float D[16];
#pragma unroll
                for (int s2 = 0; s2 < 16; ++s2) {
                    float corr = 0.f;
#pragma unroll
                    for (int c = 0; c < 16; ++c)
                        if (c < s2)
                            corr = fmaf(readlane_f(Esave[s2], J0 + c), D[c], corr);
                    float g = fmaf(rr[s2], corr, b1v[s2]);
                    const int slot = J0 + s2;
                    D[s2] = g - ov[s2];
                    gamma[((size_t)b * T_ + t0 + slot) * 64 + lane] = g;
                    ushort_t gh = f32_to_bf16(g);
                    ushort_t gl2 = f32_to_bf16(g - bf16_to_f32(gh));
                    CH[slot * 72 + lane] = gh;  CL[slot * 72 + lane] = gl2;
                    CWTh[lane * 72 + slot] = gh; CWTl[lane * 72 + slot] = gl2;
                }
            }
            // deferred A-read issue for the sub-block's last step (row J0+15)
            if (j < 3) {
                const int s15 = (j << 4) | 15;
#pragma unroll
                for (int i = 0; i < 16; ++i)
                    A[i] = *(const f32x4*)&ALPH[s15 * 68 + i * 4];
                __builtin_amdgcn_sched_barrier(0);   // pin before next sub-block
            }
        }
    }
}

// ---------- K6: prologue rows 0..63: out = LN(tanh(f)*f + f) ----------
__global__ __launch_bounds__(256) void prologue_kernel(
        const float* __restrict__ feat, float* __restrict__ out,
        const float* __restrict__ lng, const float* __restrict__ lnb) {
    int b = blockIdx.y, t = blockIdx.x, tid = threadIdx.x;
    __shared__ float red[4][2];
    size_t base = ((size_t)b * T_ + t) * D_;
    float4 f4 = *(const float4*)&feat[base + tid * 4];
    float4 y;
    y.x = tanh_fast(f4.x) * f4.x + f4.x;
    y.y = tanh_fast(f4.y) * f4.y + f4.y;
    y.z = tanh_fast(f4.z) * f4.z + f4.z;
    y.w = tanh_fast(f4.w) * f4.w + f4.w;
    float s1 = y.x + y.y + y.z + y.w;
    float s2 = y.x * y.x + y.y * y.y + y.z * y.z + y.w * y.w;
#pragma unroll
    for (int m = 1; m < 64; m <<= 1) { s1 += __shfl_xor(s1, m, 64); s2 += __shfl_xor(s2, m, 64); }
    if ((tid & 63) == 0) { red[tid >> 6][0] = s1; red[tid >> 6][1] = s2; }
    __syncthreads();
    float mu = (red[0][0] + red[1][0] + red[2][0] + red[3][0]) * (1.f / D_);
    float m2 = (red[0][1] + red[1][1] + red[2][1] + red[3][1]) * (1.f / D_);
    float rv = rsqrtf(fmaxf(m2 - mu * mu, 0.f) + LN_EPS);
    float4 g4 = *(const float4*)&lng[tid * 4];
    float4 b4 = *(const float4*)&lnb[tid * 4];
    float4 o;
    o.x = (y.x - mu) * rv * g4.x + b4.x;
    o.y = (y.y - mu) * rv * g4.y + b4.y;
    o.z = (y.z - mu) * rv * g4.z + b4.z;
    o.w = (y.w - mu) * rv * g4.w + b4.w;
    *(float4*)&out[base + tid * 4] = o;
}

// ---------- K7: V = Γ @ F0 (split-bf16 MFMA) fused with gate + LayerNorm ----------
__global__ __launch_bounds__(256) void final_kernel(
        const float* __restrict__ gamma, const ushort_t* __restrict__ fTh,
        const ushort_t* __restrict__ fTl, const float* __restrict__ feat,
        const float* __restrict__ lng, const float* __restrict__ lnb,
        float* __restrict__ out) {
    const int b = blockIdx.y;
    const int t0 = 64 + blockIdx.x * 16;
    const int tid = threadIdx.x, lane = tid & 63, wv = tid >> 6;
    const int n16 = lane & 15, quad = lane >> 4;
    __shared__ float wsum[4][16][2];
    __shared__ float lnp[16][2];

    bf16x8 Ah[2], Alo[2];
    {
        const float* gr = &gamma[((size_t)b * T_ + t0 + n16) * 64];
#pragma unroll
        for (int kt = 0; kt < 2; ++kt) {
            float g[8];
            *(float4*)&g[0] = *(const float4*)&gr[kt * 32 + quad * 8];
            *(float4*)&g[4] = *(const float4*)&gr[kt * 32 + quad * 8 + 4];
            bf16x8 h, l;
#pragma unroll
            for (int i = 0; i < 8; ++i) {
                ushort_t hh = f32_to_bf16(g[i]);
                h[i] = (short)hh;
                l[i] = (short)f32_to_bf16(g[i] - bf16_to_f32(hh));
            }
            Ah[kt] = h; Alo[kt] = l;
        }
    }
    f32x4 acc[16];
#pragma unroll
    for (int j = 0; j < 16; ++j) {
        const int d = wv * 256 + j * 16 + n16;
        const ushort_t* fr = &fTh[((size_t)b * D_ + d) * 64];
        const ushort_t* fr2 = &fTl[((size_t)b * D_ + d) * 64];
        f32x4 a = {0.f, 0.f, 0.f, 0.f};
#pragma unroll
        for (int kt = 0; kt < 2; ++kt) {
            bf16x8 bh = *(const bf16x8*)&fr[kt * 32 + quad * 8];
            bf16x8 bl = *(const bf16x8*)&fr2[kt * 32 + quad * 8];
            a = __builtin_amdgcn_mfma_f32_16x16x32_bf16(Ah[kt], bh, a, 0, 0, 0);
            a = __builtin_amdgcn_mfma_f32_16x16x32_bf16(Ah[kt], bl, a, 0, 0, 0);
            a = __builtin_amdgcn_mfma_f32_16x16x32_bf16(Alo[kt], bh, a, 0, 0, 0);
        }
        acc[j] = a;
    }
    float s1[4] = {0.f, 0.f, 0.f, 0.f}, s2[4] = {0.f, 0.f, 0.f, 0.f};
#pragma unroll
    for (int j = 0; j < 16; ++j) {
        const int d = wv * 256 + j * 16 + n16;
#pragma unroll
        for (int r = 0; r < 4; ++r) {
            float f = feat[((size_t)b * T_ + t0 + quad * 4 + r) * D_ + d];
            float y = tanh_fast(acc[j][r]) * f + f;
            acc[j][r] = y;
            s1[r] += y;
            s2[r] += y * y;
        }
    }
#pragma unroll
    for (int m = 1; m < 16; m <<= 1)
#pragma unroll
        for (int r = 0; r < 4; ++r) { s1[r] += __shfl_xor(s1[r], m, 64); s2[r] += __shfl_xor(s2[r], m, 64); }
    if (n16 == 0) {
#pragma unroll
        for (int r = 0; r < 4; ++r) { wsum[wv][quad * 4 + r][0] = s1[r]; wsum[wv][quad * 4 + r][1] = s2[r]; }
    }
    __syncthreads();
    if (tid < 16) {
        float a = 0.f, c = 0.f;
#pragma unroll
        for (int w2 = 0; w2 < 4; ++w2) { a += wsum[w2][tid][0]; c += wsum[w2][tid][1]; }
        float mu = a * (1.f / D_);
        float var = c * (1.f / D_) - mu * mu;
        lnp[tid][0] = mu;
        lnp[tid][1] = rsqrtf(fmaxf(var, 0.f) + LN_EPS);
    }
    __syncthreads();
#pragma unroll
    for (int j = 0; j < 16; ++j) {
        const int d = wv * 256 + j * 16 + n16;
        float gd = lng[d], bd = lnb[d];
#pragma unroll
        for (int r = 0; r < 4; ++r) {
            int row = quad * 4 + r;
            out[((size_t)b * T_ + t0 + row) * D_ + d] = (acc[j][r] - lnp[row][0]) * lnp[row][1] * gd + bd;
        }
    }
}

extern "C" void kernel_launch(void* const* d_in, const int* in_sizes, int n_in,
                              void* d_out, int out_size, void* d_ws, size_t ws_size,
                              hipStream_t stream) {
    const float* feature = (const float*)d_in[0];
    const float* wq_w    = (const float*)d_in[1];
    const float* wq_b    = (const float*)d_in[2];
    const float* w2_w    = (const float*)d_in[3];
    // d_in[4] = w2_b: softmax-invariant, unused
    const float* ln_g    = (const float*)d_in[5];
    const float* ln_b    = (const float*)d_in[6];
    float* out = (float*)d_out;

    uint8_t* ws = (uint8_t*)d_ws;
    // phase-1 regions
    ushort_t* featbf = (ushort_t*)(ws);                       // 32 MB (dead after gemm_qw)
    ushort_t* wqT    = (ushort_t*)(ws + 32u * 1024 * 1024);   // 2 MB
    // phase-2 regions (alias featbf space)
    float*    gamma = (float*)(ws);                           // 4 MB
    ushort_t* S0h   = (ushort_t*)(ws + 4u * 1024 * 1024);     // 2 MB
    ushort_t* S0l   = (ushort_t*)(ws + 6u * 1024 * 1024);     // 2 MB
    float*    fT32  = (float*)(ws + 8u * 1024 * 1024);        // 2 MB
    ushort_t* fTh   = (ushort_t*)(ws + 10u * 1024 * 1024);    // 1 MB
    ushort_t* fTl   = (ushort_t*)(ws + 11u * 1024 * 1024);    // 1 MB

    const int ntot = B_ * T_ * D_;
    cvt_feat<<<(ntot + 255) / 256, 256, 0, stream>>>(feature, featbf, ntot);
    cvt_wqT<<<dim3(16, 16), 256, 0, stream>>>(wq_w, wqT);
    gemm_qw<<<dim3(128, 16), 256, 0, stream>>>(featbf, wqT, wq_b, w2_w, out);
    featT_kernel<<<dim3(16, 8), 256, 0, stream>>>(feature, fT32, fTh, fTl);
    s0_gemm<<<dim3(31, 8), 256, 0, stream>>>(out, fT32, S0h, S0l);
    core_kernel<<<8, 64, 0, stream>>>(S0h, S0l, gamma);
    prologue_kernel<<<dim3(64, 8), 256, 0, stream>>>(feature, out, ln_g, ln_b);
    final_kernel<<<dim3(124, 8), 256, 0, stream>>>(gamma, fTh, fTl, feature, ln_g, ln_b, out);
}

// Round 6
// 1373.467 us; speedup vs baseline: 1.0367x; 1.0267x over previous
//
#include <hip/hip_runtime.h>
#include <hip/hip_bf16.h>

#define B_ 8
#define T_ 2048
#define D_ 1024
#define W_ 64
#define LN_EPS 1e-5f
#define LOG2E 1.4426950408889634f

typedef __attribute__((ext_vector_type(8))) short bf16x8;
typedef __attribute__((ext_vector_type(4))) float f32x4;
typedef __attribute__((ext_vector_type(2))) float f32x2;
typedef unsigned short ushort_t;

__device__ __forceinline__ ushort_t f32_to_bf16(float f) {
    union { float ff; unsigned u; } c; c.ff = f;
    unsigned r = (c.u + 0x7fffu + ((c.u >> 16) & 1u)) >> 16;
    return (ushort_t)r;
}
__device__ __forceinline__ float bf16_to_f32(ushort_t h) {
    union { unsigned u; float f; } c; c.u = ((unsigned)h) << 16; return c.f;
}
__device__ __forceinline__ float tanh_fast(float x) {
    float xx = fminf(fmaxf(x, -20.f), 20.f);
    float e = __expf(2.f * xx);
    return 1.f - 2.f / (e + 1.f);
}
__device__ __forceinline__ float readlane_f(float v, int l) {
    return __int_as_float(__builtin_amdgcn_readlane(__float_as_int(v), l));
}
// DPP-based add with immediate control (template => constant integer)
template <int CTRL>
__device__ __forceinline__ float dpp_add(float x) {
    int y = __builtin_amdgcn_update_dpp(0, __float_as_int(x), CTRL, 0xf, 0xf, true);
    return x + __int_as_float(y);
}
// Packed pair reduction: one DPP chain reduces both components.
template <int CTRL>
__device__ __forceinline__ f32x2 pk_dpp_add(f32x2 v) {
    f32x2 t;
    t.x = __int_as_float(__builtin_amdgcn_update_dpp(0, __float_as_int(v.x), CTRL, 0xf, 0xf, true));
    t.y = __int_as_float(__builtin_amdgcn_update_dpp(0, __float_as_int(v.y), CTRL, 0xf, 0xf, true));
    return v + t;
}
__device__ __forceinline__ f32x2 sum64_pair(f32x2 v) {
    v = pk_dpp_add<0x111>(v);  // row_shr:1
    v = pk_dpp_add<0x112>(v);  // row_shr:2
    v = pk_dpp_add<0x114>(v);  // row_shr:4
    v = pk_dpp_add<0x118>(v);  // row_shr:8
    v = pk_dpp_add<0x142>(v);  // row_bcast:15
    v = pk_dpp_add<0x143>(v);  // row_bcast:31 -> lane63 = totals
    return v;
}
__device__ __forceinline__ f32x2 lo2(f32x4 v) { return __builtin_shufflevector(v, v, 0, 1); }
__device__ __forceinline__ f32x2 hi2(f32x4 v) { return __builtin_shufflevector(v, v, 2, 3); }

// ---------- K0: feature -> bf16 ----------
__global__ void cvt_feat(const float* __restrict__ f, ushort_t* __restrict__ o, int n) {
    int i = blockIdx.x * blockDim.x + threadIdx.x;
    if (i < n) o[i] = f32_to_bf16(f[i]);
}

// ---------- K1: wqT[n][k] = bf16(wq[k][n]) ----------
__global__ void cvt_wqT(const float* __restrict__ wq, ushort_t* __restrict__ o) {
    __shared__ float tile[64][65];
    int bi = blockIdx.x, bj = blockIdx.y, tid = threadIdx.x;
    int c = tid & 63, r4 = tid >> 6;
    for (int it = 0; it < 16; ++it) {
        int r = it * 4 + r4;
        tile[r][c] = wq[(size_t)(bi * 64 + r) * D_ + bj * 64 + c];
    }
    __syncthreads();
    for (int it = 0; it < 16; ++it) {
        int r = it * 4 + r4;
        o[(size_t)(bj * 64 + r) * D_ + bi * 64 + c] = f32_to_bf16(tile[c][r]);
    }
}

// ---------- K2: qw = (featbf @ wqT^T + wq_b) * w2_w * log2(e)  (MFMA bf16) ----------
__global__ __launch_bounds__(256) void gemm_qw(
        const ushort_t* __restrict__ A, const ushort_t* __restrict__ BT,
        const float* __restrict__ wqb, const float* __restrict__ w2w,
        float* __restrict__ out) {
    const int K = 1024;
    __shared__ ushort_t Al[128][48];
    __shared__ ushort_t Bl[64][48];
    int tid = threadIdx.x;
    int lane = tid & 63, wv = tid >> 6;
    int wm = wv >> 1, wn = wv & 1;
    int m0 = blockIdx.x * 128, n0 = blockIdx.y * 64;
    int mrow = lane & 15, quad = lane >> 4;
    f32x4 acc[4][2] = {};
    for (int k0 = 0; k0 < K; k0 += 32) {
#pragma unroll
        for (int rep = 0; rep < 2; ++rep) {
            int idx = rep * 256 + tid;
            int r = idx >> 2, cp = (idx & 3) * 8;
            *(bf16x8*)&Al[r][cp] = *(const bf16x8*)&A[(size_t)(m0 + r) * K + k0 + cp];
        }
        {
            int r = tid >> 2, cp = (tid & 3) * 8;
            *(bf16x8*)&Bl[r][cp] = *(const bf16x8*)&BT[(size_t)(n0 + r) * K + k0 + cp];
        }
        __syncthreads();
        bf16x8 af[4], bfr[2];
#pragma unroll
        for (int ms = 0; ms < 4; ++ms) af[ms] = *(bf16x8*)&Al[wm * 64 + ms * 16 + mrow][quad * 8];
#pragma unroll
        for (int ns = 0; ns < 2; ++ns) bfr[ns] = *(bf16x8*)&Bl[wn * 32 + ns * 16 + mrow][quad * 8];
#pragma unroll
        for (int ms = 0; ms < 4; ++ms)
#pragma unroll
            for (int ns = 0; ns < 2; ++ns)
                acc[ms][ns] = __builtin_amdgcn_mfma_f32_16x16x32_bf16(af[ms], bfr[ns], acc[ms][ns], 0, 0, 0);
        __syncthreads();
    }
#pragma unroll
    for (int ns = 0; ns < 2; ++ns) {
        int n = n0 + wn * 32 + ns * 16 + mrow;
        float scale = w2w[n] * LOG2E, bias = wqb[n];
#pragma unroll
        for (int ms = 0; ms < 4; ++ms) {
#pragma unroll
            for (int r = 0; r < 4; ++r) {
                int m = m0 + wm * 64 + ms * 16 + quad * 4 + r;
                out[(size_t)m * D_ + n] = (acc[ms][ns][r] + bias) * scale;
            }
        }
    }
}

// ---------- K3: transpose first 64 feature rows: fT32/fTh/fTl [b][d][w] ----------
__global__ void featT_kernel(const float* __restrict__ feat, float* __restrict__ fT32,
                             ushort_t* __restrict__ fTh, ushort_t* __restrict__ fTl) {
    __shared__ float tile[64][65];
    int d0 = blockIdx.x * 64, b = blockIdx.y, tid = threadIdx.x;
    int c = tid & 63, r4 = tid >> 6;
#pragma unroll
    for (int it = 0; it < 16; ++it) {
        int r = it * 4 + r4;
        tile[r][c] = feat[((size_t)b * T_ + r) * D_ + d0 + c];
    }
    __syncthreads();
#pragma unroll
    for (int it = 0; it < 16; ++it) {
        int r = it * 4 + r4;
        float v = tile[c][r];
        size_t o = ((size_t)b * D_ + d0 + r) * 64 + c;
        fT32[o] = v;
        ushort_t h = f32_to_bf16(v);
        fTh[o] = h;
        fTl[o] = f32_to_bf16(v - bf16_to_f32(h));
    }
}

// ---------- K4: S0[b][t][w] = qw[b][t]·F0[b][w]  (fp32, stored as bf16 hi/lo) ----------
__global__ __launch_bounds__(256) void s0_gemm(
        const float* __restrict__ qw, const float* __restrict__ fT32,
        ushort_t* __restrict__ S0h, ushort_t* __restrict__ S0l) {
    __shared__ float As[64][17];
    __shared__ float Bs[16][65];
    int b = blockIdx.y;
    int t0 = 64 + blockIdx.x * 64;
    int tx = threadIdx.x & 15, ty = threadIdx.x >> 4;
    float acc[4][4] = {};
    for (int k0 = 0; k0 < D_; k0 += 16) {
#pragma unroll
        for (int i = 0; i < 4; ++i) {
            int idx = i * 256 + threadIdx.x;
            int r = idx >> 4, c = idx & 15;
            As[r][c] = qw[((size_t)b * T_ + t0 + r) * D_ + k0 + c];
        }
#pragma unroll
        for (int i = 0; i < 4; ++i) {
            int idx = i * 256 + threadIdx.x;
            int r = idx >> 6, c = idx & 63;
            Bs[r][c] = fT32[((size_t)b * D_ + k0 + r) * 64 + c];
        }
        __syncthreads();
#pragma unroll
        for (int kk = 0; kk < 16; ++kk)
#pragma unroll
            for (int i = 0; i < 4; ++i)
#pragma unroll
                for (int j = 0; j < 4; ++j)
                    acc[i][j] = fmaf(As[ty * 4 + i][kk], Bs[kk][tx * 4 + j], acc[i][j]);
        __syncthreads();
    }
#pragma unroll
    for (int i = 0; i < 4; ++i)
#pragma unroll
        for (int j = 0; j < 4; ++j) {
            float sc = acc[i][j];
            ushort_t h = f32_to_bf16(sc);
            size_t o = ((size_t)b * T_ + t0 + ty * 4 + i) * 64 + tx * 4 + j;
            S0h[o] = h;
            S0l[o] = f32_to_bf16(sc - bf16_to_f32(h));
        }
}

// ---------- K5: sequential core, 1 wave per batch ----------
// CODE-SIZE fix: the j-loop over the four 16-step sub-blocks is ROLLED
// (runtime j) so the p-loop body shrinks ~4x and stays L1I-resident.
// The 16-step inner body stays unrolled (constant sl => constant register
// indices).  The only j-dependent register indexing -- which X group takes
// the column update -- is a 4-way UNIFORM scalar branch.  Step logic is the
// proven fastest variant (packed pair DPP sum, nxt patched via readlane
// with runtime-uniform lane index).
__global__ __launch_bounds__(64, 1) void core_kernel(
        const ushort_t* __restrict__ S0h, const ushort_t* __restrict__ S0l,
        float* __restrict__ gamma) {
    const int b = blockIdx.x;
    const int lane = threadIdx.x;
    const int n16 = lane & 15, quad = lane >> 4;
    __shared__ float ULDS[64 * 67];          // Z: row=pos, col=slot
    __shared__ __align__(16) float ALPH[64 * 68];  // e matrix; col64 = rtot
    __shared__ __align__(16) float B1L[16 * 68];   // sub-block Gamma staging
    __shared__ ushort_t CH[64 * 72];         // C rows   [slot][basis]  bf16 hi
    __shared__ ushort_t CL[64 * 72];
    __shared__ ushort_t CWTh[64 * 72];       // C^T rows [basis][slot]  bf16 hi
    __shared__ ushort_t CWTl[64 * 72];

#pragma unroll
    for (int jj = 0; jj < 72; ++jj) {
        ushort_t idv = (jj == lane) ? (ushort_t)0x3F80 : (ushort_t)0;
        CH[lane * 72 + jj] = idv;  CL[lane * 72 + jj] = 0;
        CWTh[lane * 72 + jj] = idv; CWTl[lane * 72 + jj] = 0;
    }
    // single wave: DS pipe is in-order per wave; no barriers needed.

#pragma unroll 1
    for (int p = 0; p < 31; ++p) {
        const int t0 = 64 + (p << 6);

        // ---- Lpre = S0sup @ C^T via split-bf16 MFMA -> ULDS ----
        {
            bf16x8 Bh[4][2], Blo[4][2];
#pragma unroll
            for (int nt = 0; nt < 4; ++nt)
#pragma unroll
                for (int kt = 0; kt < 2; ++kt) {
                    int a = (nt * 16 + n16) * 72 + kt * 32 + quad * 8;
                    Bh[nt][kt] = *(const bf16x8*)&CH[a];
                    Blo[nt][kt] = *(const bf16x8*)&CL[a];
                }
#pragma unroll
            for (int mt = 0; mt < 4; ++mt) {
                bf16x8 Ah[2], Alo2[2];
#pragma unroll
                for (int kt = 0; kt < 2; ++kt) {
                    size_t a = ((size_t)b * T_ + t0 + mt * 16 + n16) * 64 + kt * 32 + quad * 8;
                    Ah[kt] = *(const bf16x8*)&S0h[a];
                    Alo2[kt] = *(const bf16x8*)&S0l[a];
                }
                f32x4 acc[4] = {};
#pragma unroll
                for (int nt = 0; nt < 4; ++nt)
#pragma unroll
                    for (int kt = 0; kt < 2; ++kt) {
                        acc[nt] = __builtin_amdgcn_mfma_f32_16x16x32_bf16(Ah[kt], Bh[nt][kt], acc[nt], 0, 0, 0);
                        acc[nt] = __builtin_amdgcn_mfma_f32_16x16x32_bf16(Ah[kt], Blo[nt][kt], acc[nt], 0, 0, 0);
                        acc[nt] = __builtin_amdgcn_mfma_f32_16x16x32_bf16(Alo2[kt], Bh[nt][kt], acc[nt], 0, 0, 0);
                    }
#pragma unroll
                for (int nt = 0; nt < 4; ++nt)
#pragma unroll
                    for (int r = 0; r < 4; ++r)
                        ULDS[(mt * 16 + quad * 4 + r) * 67 + nt * 16 + n16] = acc[nt][r];
            }
        }

        // X (lane = time position, index = slot) as f32x2 pairs, constant-indexed
        f32x2 Xa2[8], Xb2[8], Xc2[8], Xd2[8];
#pragma unroll
        for (int l2 = 0; l2 < 8; ++l2) {
            Xa2[l2].x = ULDS[lane * 67 + 2 * l2];
            Xa2[l2].y = ULDS[lane * 67 + 2 * l2 + 1];
            Xb2[l2].x = ULDS[lane * 67 + 16 + 2 * l2];
            Xb2[l2].y = ULDS[lane * 67 + 16 + 2 * l2 + 1];
            Xc2[l2].x = ULDS[lane * 67 + 32 + 2 * l2];
            Xc2[l2].y = ULDS[lane * 67 + 32 + 2 * l2 + 1];
            Xd2[l2].x = ULDS[lane * 67 + 48 + 2 * l2];
            Xd2[l2].y = ULDS[lane * 67 + 48 + 2 * l2 + 1];
        }
        float row = ULDS[lane];           // Z row 0 (fresh from Lpre)
        float nxt = ULDS[67 + lane];      // Z row 1

#pragma unroll 1
        for (int j = 0; j < 4; ++j) {     // ROLLED: runtime j, uniform branches
#pragma unroll
            for (int sl = 0; sl < 16; ++sl) {
                const int s = (j << 4) | sl;          // runtime via j
                // guards: compile-time true for sl<=13 / sl<15; runtime (j<3) else
                const bool c61 = (sl <= 13);
                const bool c63 = (sl <= 14);
                bool do61 = c61 || (j < 3);           // s <= 61
                bool do63 = c63 || (j < 3);           // s < 63
                float e = __builtin_amdgcn_exp2f(row);   // logits pre-scaled by log2e
                ALPH[s * 68 + lane] = e;                 // raw e (div deferred)
                f32x4 A[16];
                if (do63) {
#pragma unroll
                    for (int i = 0; i < 16; ++i)
                        A[i] = *(const f32x4*)&ALPH[s * 68 + i * 4];
                }
                // read row s+2 BEFORE this step's u_new write; stale col s
                // patched from registers below.
                float nxt2v = 0.f;
                if (do61) nxt2v = ULDS[(s + 2) * 67 + lane];
                // one packed DPP chain: {denominator, critical dot}
                f32x2 v; v.x = e; v.y = e * nxt;
                v = sum64_pair(v);
                float tot = readlane_f(v.x, 63) + 1.f;   // + 2^0 zero-row
                float cs  = readlane_f(v.y, 63);
                float r = __builtin_amdgcn_rcpf(tot);
                if (do63) {
                    float u_next = cs * r;               // u[s+1] (critical element)
                    // bulk matvec on packed pairs (v_pk_fma_f32)
                    f32x2 acc0 = {0.f, 0.f}, acc1 = {0.f, 0.f}, acc2 = {0.f, 0.f}, acc3 = {0.f, 0.f};
#pragma unroll
                    for (int i2 = 0; i2 < 4; ++i2) {
                        f32x4 aa = A[i2];
                        acc0 = __builtin_elementwise_fma(lo2(aa), Xa2[2 * i2], acc0);
                        acc1 = __builtin_elementwise_fma(hi2(aa), Xa2[2 * i2 + 1], acc1);
                        f32x4 ab = A[4 + i2];
                        acc2 = __builtin_elementwise_fma(lo2(ab), Xb2[2 * i2], acc2);
                        acc3 = __builtin_elementwise_fma(hi2(ab), Xb2[2 * i2 + 1], acc3);
                        f32x4 ac = A[8 + i2];
                        acc0 = __builtin_elementwise_fma(lo2(ac), Xc2[2 * i2], acc0);
                        acc1 = __builtin_elementwise_fma(hi2(ac), Xc2[2 * i2 + 1], acc1);
                        f32x4 ad = A[12 + i2];
                        acc2 = __builtin_elementwise_fma(lo2(ad), Xd2[2 * i2], acc2);
                        acc3 = __builtin_elementwise_fma(hi2(ad), Xd2[2 * i2 + 1], acc3);
                    }
                    f32x2 u2 = (acc0 + acc1) + (acc2 + acc3);
                    float u_new = (u2.x + u2.y) * r;
                    // X column update: col = s -> group selected by UNIFORM j branch,
                    // element index is compile-time (sl).
                    if (j == 0)      { if (sl & 1) Xa2[sl >> 1].y = u_new; else Xa2[sl >> 1].x = u_new; }
                    else if (j == 1) { if (sl & 1) Xb2[sl >> 1].y = u_new; else Xb2[sl >> 1].x = u_new; }
                    else if (j == 2) { if (sl & 1) Xc2[sl >> 1].y = u_new; else Xc2[sl >> 1].x = u_new; }
                    else             { if (sl & 1) Xd2[sl >> 1].y = u_new; else Xd2[sl >> 1].x = u_new; }
                    if (lane > s) ULDS[lane * 67 + s] = u_new;
                    // register carry: patch stale col s of row s+2 via readlane
                    // (runtime-uniform lane index s+2 -> SGPR select)
                    row = (lane == s) ? u_next : nxt;
                    if (do61) {
                        float pu = readlane_f(u_new, s + 2);
                        nxt = (lane == s) ? pu : nxt2v;
                    } else {
                        nxt = 0.f;
                    }
                }
                if (lane == 0) ALPH[s * 68 + 64] = r;    // stash rtot for Gamma
            }

            // ---- Gamma for sub-block j: B1 = A_J @ CW_preJ (MFMA), then correction ----
            {
                const int J0 = j << 4;
                float rrow = ALPH[(J0 + n16) * 68 + 64];   // rtot of this lane's row
                bf16x8 Aah[2], Aal[2];
#pragma unroll
                for (int kt = 0; kt < 2; ++kt) {
                    float v[8];
                    *(float4*)&v[0] = *(const float4*)&ALPH[(J0 + n16) * 68 + kt * 32 + quad * 8];
                    *(float4*)&v[4] = *(const float4*)&ALPH[(J0 + n16) * 68 + kt * 32 + quad * 8 + 4];
                    bf16x8 h, l;
#pragma unroll
                    for (int i = 0; i < 8; ++i) {
                        float val = v[i] * rrow;           // alpha = e * rtot
                        ushort_t hh = f32_to_bf16(val);
                        h[i] = (short)hh;
                        l[i] = (short)f32_to_bf16(val - bf16_to_f32(hh));
                    }
                    Aah[kt] = h; Aal[kt] = l;
                }
#pragma unroll
                for (int nt = 0; nt < 4; ++nt) {
                    f32x4 a = {};
#pragma unroll
                    for (int kt = 0; kt < 2; ++kt) {
                        bf16x8 bh = *(const bf16x8*)&CWTh[(nt * 16 + n16) * 72 + kt * 32 + quad * 8];
                        bf16x8 bl = *(const bf16x8*)&CWTl[(nt * 16 + n16) * 72 + kt * 32 + quad * 8];
                        a = __builtin_amdgcn_mfma_f32_16x16x32_bf16(Aah[kt], bh, a, 0, 0, 0);
                        a = __builtin_amdgcn_mfma_f32_16x16x32_bf16(Aah[kt], bl, a, 0, 0, 0);
                        a = __builtin_amdgcn_mfma_f32_16x16x32_bf16(Aal[kt], bh, a, 0, 0, 0);
                    }
#pragma unroll
                    for (int r = 0; r < 4; ++r)
                        B1L[(quad * 4 + r) * 68 + nt * 16 + n16] = a[r];
                }
                // triangular correction sweep (lane = basis column)
                float D[16];
#pragma unroll
                for (int sl = 0; sl < 16; ++sl) {
                    float corr = 0.f;
                    const float* arow = &ALPH[(J0 + sl) * 68 + J0];   // raw e values
#pragma unroll
                    for (int c = 0; c < 4; ++c) {
                        if (sl > 4 * c) {
                            float4 am = *(const float4*)&arow[4 * c];
                            if (sl > 4 * c + 0) corr = fmaf(am.x, D[4 * c + 0], corr);
                            if (sl > 4 * c + 1) corr = fmaf(am.y, D[4 * c + 1], corr);
                            if (sl > 4 * c + 2) corr = fmaf(am.z, D[4 * c + 2], corr);
                            if (sl > 4 * c + 3) corr = fmaf(am.w, D[4 * c + 3], corr);
                        }
                    }
                    float rsl = ALPH[(J0 + sl) * 68 + 64];            // broadcast rtot
                    float g = fmaf(rsl, corr, B1L[sl * 68 + lane]);
                    const int slot = J0 + sl;
                    float oldv = bf16_to_f32(CH[slot * 72 + lane]) + bf16_to_f32(CL[slot * 72 + lane]);
                    D[sl] = g - oldv;
                    gamma[((size_t)b * T_ + t0 + slot) * 64 + lane] = g;
                    ushort_t gh = f32_to_bf16(g);
                    ushort_t gl2 = f32_to_bf16(g - bf16_to_f32(gh));
                    CH[slot * 72 + lane] = gh;  CL[slot * 72 + lane] = gl2;
                    CWTh[lane * 72 + slot] = gh; CWTl[lane * 72 + slot] = gl2;
                }
            }
        }
    }
}

// ---------- K6: prologue rows 0..63: out = LN(tanh(f)*f + f) ----------
__global__ __launch_bounds__(256) void prologue_kernel(
        const float* __restrict__ feat, float* __restrict__ out,
        const float* __restrict__ lng, const float* __restrict__ lnb) {
    int b = blockIdx.y, t = blockIdx.x, tid = threadIdx.x;
    __shared__ float red[4][2];
    size_t base = ((size_t)b * T_ + t) * D_;
    float4 f4 = *(const float4*)&feat[base + tid * 4];
    float4 y;
    y.x = tanh_fast(f4.x) * f4.x + f4.x;
    y.y = tanh_fast(f4.y) * f4.y + f4.y;
    y.z = tanh_fast(f4.z) * f4.z + f4.z;
    y.w = tanh_fast(f4.w) * f4.w + f4.w;
    float s1 = y.x + y.y + y.z + y.w;
    float s2 = y.x * y.x + y.y * y.y + y.z * y.z + y.w * y.w;
#pragma unroll
    for (int m = 1; m < 64; m <<= 1) { s1 += __shfl_xor(s1, m, 64); s2 += __shfl_xor(s2, m, 64); }
    if ((tid & 63) == 0) { red[tid >> 6][0] = s1; red[tid >> 6][1] = s2; }
    __syncthreads();
    float mu = (red[0][0] + red[1][0] + red[2][0] + red[3][0]) * (1.f / D_);
    float m2 = (red[0][1] + red[1][1] + red[2][1] + red[3][1]) * (1.f / D_);
    float rv = rsqrtf(fmaxf(m2 - mu * mu, 0.f) + LN_EPS);
    float4 g4 = *(const float4*)&lng[tid * 4];
    float4 b4 = *(const float4*)&lnb[tid * 4];
    float4 o;
    o.x = (y.x - mu) * rv * g4.x + b4.x;
    o.y = (y.y - mu) * rv * g4.y + b4.y;
    o.z = (y.z - mu) * rv * g4.z + b4.z;
    o.w = (y.w - mu) * rv * g4.w + b4.w;
    *(float4*)&out[base + tid * 4] = o;
}

// ---------- K7: V = Γ @ F0 (split-bf16 MFMA) fused with gate + LayerNorm ----------
__global__ __launch_bounds__(256) void final_kernel(
        const float* __restrict__ gamma, const ushort_t* __restrict__ fTh,
        const ushort_t* __restrict__ fTl, const float* __restrict__ feat,
        const float* __restrict__ lng, const float* __restrict__ lnb,
        float* __restrict__ out) {
    const int b = blockIdx.y;
    const int t0 = 64 + blockIdx.x * 16;
    const int tid = threadIdx.x, lane = tid & 63, wv = tid >> 6;
    const int n16 = lane & 15, quad = lane >> 4;
    __shared__ float wsum[4][16][2];
    __shared__ float lnp[16][2];

    bf16x8 Ah[2], Alo[2];
    {
        const float* gr = &gamma[((size_t)b * T_ + t0 + n16) * 64];
#pragma unroll
        for (int kt = 0; kt < 2; ++kt) {
            float g[8];
            *(float4*)&g[0] = *(const float4*)&gr[kt * 32 + quad * 8];
            *(float4*)&g[4] = *(const float4*)&gr[kt * 32 + quad * 8 + 4];
            bf16x8 h, l;
#pragma unroll
            for (int i = 0; i < 8; ++i) {
                ushort_t hh = f32_to_bf16(g[i]);
                h[i] = (short)hh;
                l[i] = (short)f32_to_bf16(g[i] - bf16_to_f32(hh));
            }
            Ah[kt] = h; Alo[kt] = l;
        }
    }
    f32x4 acc[16];
#pragma unroll
    for (int j = 0; j < 16; ++j) {
        const int d = wv * 256 + j * 16 + n16;
        const ushort_t* fr = &fTh[((size_t)b * D_ + d) * 64];
        const ushort_t* fr2 = &fTl[((size_t)b * D_ + d) * 64];
        f32x4 a = {0.f, 0.f, 0.f, 0.f};
#pragma unroll
        for (int kt = 0; kt < 2; ++kt) {
            bf16x8 bh = *(const bf16x8*)&fr[kt * 32 + quad * 8];
            bf16x8 bl = *(const bf16x8*)&fr2[kt * 32 + quad * 8];
            a = __builtin_amdgcn_mfma_f32_16x16x32_bf16(Ah[kt], bh, a, 0, 0, 0);
            a = __builtin_amdgcn_mfma_f32_16x16x32_bf16(Ah[kt], bl, a, 0, 0, 0);
            a = __builtin_amdgcn_mfma_f32_16x16x32_bf16(Alo[kt], bh, a, 0, 0, 0);
        }
        acc[j] = a;
    }
    float s1[4] = {0.f, 0.f, 0.f, 0.f}, s2[4] = {0.f, 0.f, 0.f, 0.f};
#pragma unroll
    for (int j = 0; j < 16; ++j) {
        const int d = wv * 256 + j * 16 + n16;
#pragma unroll
        for (int r = 0; r < 4; ++r) {
            float f = feat[((size_t)b * T_ + t0 + quad * 4 + r) * D_ + d];
            float y = tanh_fast(acc[j][r]) * f + f;
            acc[j][r] = y;
            s1[r] += y;
            s2[r] += y * y;
        }
    }
#pragma unroll
    for (int m = 1; m < 16; m <<= 1)
#pragma unroll
        for (int r = 0; r < 4; ++r) { s1[r] += __shfl_xor(s1[r], m, 64); s2[r] += __shfl_xor(s2[r], m, 64); }
    if (n16 == 0) {
#pragma unroll
        for (int r = 0; r < 4; ++r) { wsum[wv][quad * 4 + r][0] = s1[r]; wsum[wv][quad * 4 + r][1] = s2[r]; }
    }
    __syncthreads();
    if (tid < 16) {
        float a = 0.f, c = 0.f;
#pragma unroll
        for (int w2 = 0; w2 < 4; ++w2) { a += wsum[w2][tid][0]; c += wsum[w2][tid][1]; }
        float mu = a * (1.f / D_);
        float var = c * (1.f / D_) - mu * mu;
        lnp[tid][0] = mu;
        lnp[tid][1] = rsqrtf(fmaxf(var, 0.f) + LN_EPS);
    }
    __syncthreads();
#pragma unroll
    for (int j = 0; j < 16; ++j) {
        const int d = wv * 256 + j * 16 + n16;
        float gd = lng[d], bd = lnb[d];
#pragma unroll
        for (int r = 0; r < 4; ++r) {
            int row = quad * 4 + r;
            out[((size_t)b * T_ + t0 + row) * D_ + d] = (acc[j][r] - lnp[row][0]) * lnp[row][1] * gd + bd;
        }
    }
}

extern "C" void kernel_launch(void* const* d_in, const int* in_sizes, int n_in,
                              void* d_out, int out_size, void* d_ws, size_t ws_size,
                              hipStream_t stream) {
    const float* feature = (const float*)d_in[0];
    const float* wq_w    = (const float*)d_in[1];
    const float* wq_b    = (const float*)d_in[2];
    const float* w2_w    = (const float*)d_in[3];
    // d_in[4] = w2_b: softmax-invariant, unused
    const float* ln_g    = (const float*)d_in[5];
    const float* ln_b    = (const float*)d_in[6];
    float* out = (float*)d_out;

    uint8_t* ws = (uint8_t*)d_ws;
    // phase-1 regions
    ushort_t* featbf = (ushort_t*)(ws);                       // 32 MB (dead after gemm_qw)
    ushort_t* wqT    = (ushort_t*)(ws + 32u * 1024 * 1024);   // 2 MB
    // phase-2 regions (alias featbf space)
    float*    gamma = (float*)(ws);                           // 4 MB
    ushort_t* S0h   = (ushort_t*)(ws + 4u * 1024 * 1024);     // 2 MB
    ushort_t* S0l   = (ushort_t*)(ws + 6u * 1024 * 1024);     // 2 MB
    float*    fT32  = (float*)(ws + 8u * 1024 * 1024);        // 2 MB
    ushort_t* fTh   = (ushort_t*)(ws + 10u * 1024 * 1024);    // 1 MB
    ushort_t* fTl   = (ushort_t*)(ws + 11u * 1024 * 1024);    // 1 MB

    const int ntot = B_ * T_ * D_;
    cvt_feat<<<(ntot + 255) / 256, 256, 0, stream>>>(feature, featbf, ntot);
    cvt_wqT<<<dim3(16, 16), 256, 0, stream>>>(wq_w, wqT);
    gemm_qw<<<dim3(128, 16), 256, 0, stream>>>(featbf, wqT, wq_b, w2_w, out);
    featT_kernel<<<dim3(16, 8), 256, 0, stream>>>(feature, fT32, fTh, fTl);
    s0_gemm<<<dim3(31, 8), 256, 0, stream>>>(out, fT32, S0h, S0l);
    core_kernel<<<8, 64, 0, stream>>>(S0h, S0l, gamma);
    prologue_kernel<<<dim3(64, 8), 256, 0, stream>>>(feature, out, ln_g, ln_b);
    final_kernel<<<dim3(124, 8), 256, 0, stream>>>(gamma, fTh, fTl, feature, ln_g, ln_b, out);
}